// Round 3
// baseline (512.842 us; speedup 1.0000x reference)
//
#include <hip/hip_runtime.h>

#define Tdim 200
#define Ddim 128
#define Hdim 64
#define NBS  3200
#define NEGV (-1e10f)

typedef __bf16 bf16x8 __attribute__((ext_vector_type(8)));
typedef float  floatx4 __attribute__((ext_vector_type(4)));
typedef unsigned short ushort8 __attribute__((ext_vector_type(8)));

__device__ __forceinline__ unsigned short bf16rne(float f) {
    unsigned int u = __float_as_uint(f);
    u += 0x7fffu + ((u >> 16) & 1u);          // round-to-nearest-even (inputs are finite)
    return (unsigned short)(u >> 16);
}

__device__ __forceinline__ float ftanh(float x) {
    // tanh(x) = 1 - 2/(exp(2x)+1); overflow -> rcp(inf)=0 -> 1 (correct tail)
    float e = __expf(2.0f * x);
    return 1.0f - 2.0f * __builtin_amdgcn_rcpf(e + 1.0f);
}

// ---- prep: blocks 0..799 compute w2h (one thread per (bs,h)); blocks 800..803 convert W1 to bf16
__global__ void prep(const float* __restrict__ z, const float* __restrict__ W2w,
                     const float* __restrict__ W2b, const float* __restrict__ W1,
                     unsigned short* __restrict__ W1bf, float* __restrict__ w2h) {
    const int tid = threadIdx.x;
    if (blockIdx.x < 800) {
        const int idx = blockIdx.x * 256 + tid;   // (bs,h); bs wave-uniform -> z via s_load
        const int bs = idx >> 6, h = idx & 63;
        const float* zp = z + bs * 128;
        const float* wp = W2w + h * 128;
        float a = W2b[h];
        #pragma unroll 8
        for (int d = 0; d < 128; ++d) a = fmaf(zp[d], wp[d], a);
        w2h[idx] = a;
    } else {
        const int idx = (blockIdx.x - 800) * 256 + tid;   // 0..1023, 8 floats each
        const float4* src = (const float4*)W1 + idx * 2;
        float4 v0 = src[0], v1 = src[1];
        uint4 o;
        o.x = bf16rne(v0.x) | ((unsigned int)bf16rne(v0.y) << 16);
        o.y = bf16rne(v0.z) | ((unsigned int)bf16rne(v0.w) << 16);
        o.z = bf16rne(v1.x) | ((unsigned int)bf16rne(v1.y) << 16);
        o.w = bf16rne(v1.z) | ((unsigned int)bf16rne(v1.w) << 16);
        ((uint4*)W1bf)[idx] = o;
    }
}

// ---- main: one block (4 waves) per (b,s). No LDS X tile: A-fragments load
// directly from global (each X element feeds exactly one lane; n-tile reuse is
// in registers), so LDS staging bought nothing. LDS ~5 KB -> VGPR-bound occupancy.
__global__ __launch_bounds__(256, 4) void attn_main(
    const float* __restrict__ X, const int* __restrict__ mask,
    const float* __restrict__ Vw, const float* __restrict__ Vb,
    const unsigned short* __restrict__ W1bf, const float* __restrict__ w2h_g,
    float* __restrict__ out)
{
    __shared__ float attL[Tdim];
    __shared__ float red[8];
    __shared__ float4 pf[256];

    const int tid = threadIdx.x;
    const int bs  = blockIdx.x;
    const float* __restrict__ Xb = X + (size_t)bs * (Tdim * Ddim);

    const int lane = tid & 63;
    const int wv   = tid >> 6;
    const int l15  = lane & 15, quad = lane >> 4;

    // ---- B fragments: B[n][k] = W1[h=n*16+l15][d=k]; lane holds k = ks*32+quad*8 .. +8
    bf16x8 bfrag[4][4];
    #pragma unroll
    for (int n = 0; n < 4; ++n)
        #pragma unroll
        for (int ks = 0; ks < 4; ++ks)
            bfrag[n][ks] = *(const bf16x8*)(W1bf + (n * 16 + l15) * 128 + ks * 32 + quad * 8);

    const float Vb0 = Vb[0];
    float vw[4], w2[4];
    #pragma unroll
    for (int n = 0; n < 4; ++n) {
        int h = l15 + 16 * n;
        vw[n] = Vw[h];
        w2[n] = w2h_g[bs * 64 + h];
    }

    // ---- GEMM1 + logits: wave wv does m-tiles {wv, wv+4, wv+8, wv+12<13}
    // mt=12 clamps t0 to 184: rows 184..191 recomputed identically by two waves
    // -> benign same-bits double write to attL.
    for (int mt = wv; mt < 13; mt += 4) {
        const int t0 = (mt == 12) ? 184 : mt * 16;
        const int trow = t0 + l15;                   // A row for this lane
        const float* rp = Xb + trow * Ddim + quad * 8;

        bf16x8 afrag[4];
        #pragma unroll
        for (int ks = 0; ks < 4; ++ks) {             // 8 independent dwordx4 loads
            float4 a0 = *(const float4*)(rp + ks * 32);
            float4 a1 = *(const float4*)(rp + ks * 32 + 4);
            ushort8 u;
            u[0] = bf16rne(a0.x); u[1] = bf16rne(a0.y);
            u[2] = bf16rne(a0.z); u[3] = bf16rne(a0.w);
            u[4] = bf16rne(a1.x); u[5] = bf16rne(a1.y);
            u[6] = bf16rne(a1.z); u[7] = bf16rne(a1.w);
            afrag[ks] = __builtin_bit_cast(bf16x8, u);
        }

        floatx4 acc[4];
        #pragma unroll
        for (int n = 0; n < 4; ++n) acc[n] = (floatx4){0.f, 0.f, 0.f, 0.f};
        #pragma unroll
        for (int n = 0; n < 4; ++n)
            #pragma unroll
            for (int ks = 0; ks < 4; ++ks)
                acc[n] = __builtin_amdgcn_mfma_f32_16x16x32_bf16(afrag[ks], bfrag[n][ks], acc[n], 0, 0, 0);

        // C layout: col(h) = l15 (+16n), row(t) = t0 + quad*4 + r
        float s0 = 0.f, s1 = 0.f, s2 = 0.f, s3 = 0.f;
        #pragma unroll
        for (int n = 0; n < 4; ++n) {
            s0 = fmaf(ftanh(acc[n][0] + w2[n]), vw[n], s0);
            s1 = fmaf(ftanh(acc[n][1] + w2[n]), vw[n], s1);
            s2 = fmaf(ftanh(acc[n][2] + w2[n]), vw[n], s2);
            s3 = fmaf(ftanh(acc[n][3] + w2[n]), vw[n], s3);
        }
        #pragma unroll
        for (int m = 1; m < 16; m <<= 1) {           // reduce over h-lanes (same quad = same rows)
            s0 += __shfl_xor(s0, m);
            s1 += __shfl_xor(s1, m);
            s2 += __shfl_xor(s2, m);
            s3 += __shfl_xor(s3, m);
        }
        if (l15 == 0) {
            const int tb = t0 + quad * 4;
            attL[tb]     = s0 + Vb0;
            attL[tb + 1] = s1 + Vb0;
            attL[tb + 2] = s2 + Vb0;
            attL[tb + 3] = s3 + Vb0;
        }
    }
    __syncthreads();

    // ---- masked softmax over T (4 waves, shuffle + LDS combine)
    float l = -3e38f;
    if (tid < Tdim) {
        l = attL[tid];
        if (mask[bs * Tdim + tid] == 0) l = NEGV;
    }
    float m = l;
    #pragma unroll
    for (int off = 32; off > 0; off >>= 1) m = fmaxf(m, __shfl_xor(m, off));
    if (lane == 0) red[wv] = m;
    __syncthreads();
    const float M = fmaxf(fmaxf(red[0], red[1]), fmaxf(red[2], red[3]));
    float p = __expf(l - M);
    float sm = p;
    #pragma unroll
    for (int off = 32; off > 0; off >>= 1) sm += __shfl_xor(sm, off);
    if (lane == 0) red[4 + wv] = sm;
    __syncthreads();
    const float S = (red[4] + red[5]) + (red[6] + red[7]);
    if (tid < Tdim) attL[tid] = p / S;               // own-slot overwrite, race-free
    __syncthreads();

    // ---- pass 2: out[bs][d] = sum_t att[t] * X[t][d]  (float4 global re-read, L2/L3-hot)
    const int c4 = tid & 31, tg = tid >> 5;          // c4: which float4 of the row; tg: t-group
    const float4* xp = (const float4*)Xb + c4;
    float4 o = make_float4(0.f, 0.f, 0.f, 0.f);
    const int tbeg = tg * 25;
    #pragma unroll 5
    for (int tt = tbeg; tt < tbeg + 25; ++tt) {
        const float a = attL[tt];
        const float4 v = xp[tt * 32];
        o.x = fmaf(a, v.x, o.x);
        o.y = fmaf(a, v.y, o.y);
        o.z = fmaf(a, v.z, o.z);
        o.w = fmaf(a, v.w, o.w);
    }
    pf[tg * 32 + c4] = o;
    __syncthreads();
    if (tid < 32) {
        float4 s = pf[tid];
        #pragma unroll
        for (int g = 1; g < 8; ++g) {
            const float4 v = pf[g * 32 + tid];
            s.x += v.x; s.y += v.y; s.z += v.z; s.w += v.w;
        }
        *(float4*)(out + bs * Ddim + tid * 4) = s;
    }
}

extern "C" void kernel_launch(void* const* d_in, const int* in_sizes, int n_in,
                              void* d_out, int out_size, void* d_ws, size_t ws_size,
                              hipStream_t stream) {
    const float* X    = (const float*)d_in[0];
    const float* z    = (const float*)d_in[1];
    const int*   mask = (const int*)d_in[2];
    const float* W1   = (const float*)d_in[3];
    const float* W2w  = (const float*)d_in[4];
    const float* W2b  = (const float*)d_in[5];
    const float* Vw   = (const float*)d_in[6];
    const float* Vb   = (const float*)d_in[7];
    float* out = (float*)d_out;

    unsigned short* W1bf = (unsigned short*)d_ws;            // 8192 bf16 = 16 KB
    float* w2h = (float*)((char*)d_ws + 16384);              // 3200*64 fp32 = 800 KB

    prep<<<804, 256, 0, stream>>>(z, W2w, W2b, W1, W1bf, w2h);
    attn_main<<<NBS, 256, 0, stream>>>(X, mask, Vw, Vb, W1bf, w2h, out);
}

// Round 4
// 508.316 us; speedup vs baseline: 1.0089x; 1.0089x over previous
//
#include <hip/hip_runtime.h>

#define Tdim 200
#define Ddim 128
#define Hdim 64
#define NBS  3200
#define NEGV (-1e10f)

typedef __bf16 bf16x8 __attribute__((ext_vector_type(8)));
typedef float  floatx4 __attribute__((ext_vector_type(4)));
typedef unsigned short ushort8 __attribute__((ext_vector_type(8)));

__device__ __forceinline__ unsigned short bf16rne(float f) {
    unsigned int u = __float_as_uint(f);
    u += 0x7fffu + ((u >> 16) & 1u);          // round-to-nearest-even (inputs are finite)
    return (unsigned short)(u >> 16);
}

__device__ __forceinline__ float ftanh(float x) {
    // tanh(x) = 1 - 2/(exp(2x)+1); overflow -> rcp(inf)=0 -> 1 (correct tail)
    float e = __expf(2.0f * x);
    return 1.0f - 2.0f * __builtin_amdgcn_rcpf(e + 1.0f);
}

// ---- prep: blocks 0..799 compute w2h (one thread per (bs,h)); blocks 800..803 convert W1 to bf16
__global__ void prep(const float* __restrict__ z, const float* __restrict__ W2w,
                     const float* __restrict__ W2b, const float* __restrict__ W1,
                     unsigned short* __restrict__ W1bf, float* __restrict__ w2h) {
    const int tid = threadIdx.x;
    if (blockIdx.x < 800) {
        const int idx = blockIdx.x * 256 + tid;   // (bs,h); bs wave-uniform -> z via s_load
        const int bs = idx >> 6, h = idx & 63;
        const float* zp = z + bs * 128;
        const float* wp = W2w + h * 128;
        float a = W2b[h];
        #pragma unroll 8
        for (int d = 0; d < 128; ++d) a = fmaf(zp[d], wp[d], a);
        w2h[idx] = a;
    } else {
        const int idx = (blockIdx.x - 800) * 256 + tid;   // 0..1023, 8 floats each
        const float4* src = (const float4*)W1 + idx * 2;
        float4 v0 = src[0], v1 = src[1];
        uint4 o;
        o.x = bf16rne(v0.x) | ((unsigned int)bf16rne(v0.y) << 16);
        o.y = bf16rne(v0.z) | ((unsigned int)bf16rne(v0.w) << 16);
        o.z = bf16rne(v1.x) | ((unsigned int)bf16rne(v1.y) << 16);
        o.w = bf16rne(v1.z) | ((unsigned int)bf16rne(v1.w) << 16);
        ((uint4*)W1bf)[idx] = o;
    }
}

// ---- main: one block (4 waves) per (b,s). Single pass: flash-style online
// softmax + output accumulation from register-resident fp32 X values.
// W1 bfrags live in LDS (row stride 272 B -> conflict-free ds_read_b128).
__global__ __launch_bounds__(256, 3) void attn_main(
    const float* __restrict__ X, const int* __restrict__ mask,
    const float* __restrict__ Vw, const float* __restrict__ Vb,
    const unsigned short* __restrict__ W1bf, const float* __restrict__ w2h_g,
    float* __restrict__ out)
{
    __shared__ __align__(16) unsigned short w1s[64 * 136];  // 272 B rows, 17,408 B
    __shared__ int   maskS[Tdim];
    __shared__ float osum[4][128];
    __shared__ float mw[4], sw[4];

    const int tid = threadIdx.x;
    const int bs  = blockIdx.x;
    const float* __restrict__ Xb = X + (size_t)bs * (Tdim * Ddim);
    const int lane = tid & 63, wv = tid >> 6;
    const int l15 = lane & 15, quad = lane >> 4;

    // stage W1bf (16 KB) into padded LDS rows
    {
        const uint4* src = (const uint4*)W1bf;
        #pragma unroll
        for (int r = 0; r < 4; ++r) {
            int u = r * 256 + tid;               // 16B unit, 0..1023
            int h = u >> 4, i = u & 15;
            *(uint4*)((char*)w1s + h * 272 + i * 16) = src[u];
        }
    }
    if (tid < Tdim) maskS[tid] = mask[bs * Tdim + tid];

    const float Vb0 = Vb[0];
    float vw[4], w2[4];
    #pragma unroll
    for (int n = 0; n < 4; ++n) {
        int h = l15 + 16 * n;
        vw[n] = Vw[h];
        w2[n] = w2h_g[bs * 64 + h];
    }
    __syncthreads();

    float m_run = -3e38f, s_lane = 0.f;
    float opart[4][8];
    #pragma unroll
    for (int ks = 0; ks < 4; ++ks)
        #pragma unroll
        for (int j = 0; j < 8; ++j) opart[ks][j] = 0.f;

    for (int mt = wv; mt < 13; mt += 4) {
        const int t0 = (mt == 12) ? 184 : mt * 16;
        const int trow = t0 + l15;
        const float* rp = Xb + trow * Ddim + quad * 8;

        // load this lane's A-row slices (fp32, retained for the O update)
        float4 a0[4], a1[4];
        #pragma unroll
        for (int ks = 0; ks < 4; ++ks) {
            a0[ks] = *(const float4*)(rp + ks * 32);
            a1[ks] = *(const float4*)(rp + ks * 32 + 4);
        }

        floatx4 acc[4];
        #pragma unroll
        for (int n = 0; n < 4; ++n) acc[n] = (floatx4){0.f, 0.f, 0.f, 0.f};
        #pragma unroll
        for (int ks = 0; ks < 4; ++ks) {
            ushort8 u;
            u[0] = bf16rne(a0[ks].x); u[1] = bf16rne(a0[ks].y);
            u[2] = bf16rne(a0[ks].z); u[3] = bf16rne(a0[ks].w);
            u[4] = bf16rne(a1[ks].x); u[5] = bf16rne(a1[ks].y);
            u[6] = bf16rne(a1[ks].z); u[7] = bf16rne(a1[ks].w);
            const bf16x8 af = __builtin_bit_cast(bf16x8, u);
            #pragma unroll
            for (int n = 0; n < 4; ++n) {
                const bf16x8 bf = *(const bf16x8*)((char*)w1s + (n * 16 + l15) * 272 + ks * 64 + quad * 16);
                acc[n] = __builtin_amdgcn_mfma_f32_16x16x32_bf16(af, bf, acc[n], 0, 0, 0);
            }
        }

        // logits: C layout col(h)=l15+16n, row(t)=t0+quad*4+r
        float s0 = 0.f, s1 = 0.f, s2 = 0.f, s3 = 0.f;
        #pragma unroll
        for (int n = 0; n < 4; ++n) {
            s0 = fmaf(ftanh(acc[n][0] + w2[n]), vw[n], s0);
            s1 = fmaf(ftanh(acc[n][1] + w2[n]), vw[n], s1);
            s2 = fmaf(ftanh(acc[n][2] + w2[n]), vw[n], s2);
            s3 = fmaf(ftanh(acc[n][3] + w2[n]), vw[n], s3);
        }
        #pragma unroll
        for (int m = 1; m < 16; m <<= 1) {       // sum over h-lanes
            s0 += __shfl_xor(s0, m);
            s1 += __shfl_xor(s1, m);
            s2 += __shfl_xor(s2, m);
            s3 += __shfl_xor(s3, m);
        }
        // broadcast: row l15 lives in quad (l15>>2), reg (l15&3)
        const int src = (l15 >> 2) << 4;
        const float b0 = __shfl(s0, src), b1 = __shfl(s1, src);
        const float b2 = __shfl(s2, src), b3 = __shfl(s3, src);
        float lg = (l15 & 2) ? ((l15 & 1) ? b3 : b2) : ((l15 & 1) ? b1 : b0);
        lg += Vb0;
        if ((mt == 12) && (l15 < 8)) lg = -3e38f;        // rows duplicated from tile 11
        else if (maskS[trow] == 0)   lg = NEGV;

        float tm = lg;                                   // tile max over the 16 rows
        #pragma unroll
        for (int m = 1; m < 16; m <<= 1) tm = fmaxf(tm, __shfl_xor(tm, m));
        const float m_new = fmaxf(m_run, tm);
        if (m_new > m_run) {                             // wave-uniform branch
            const float alpha = __expf(m_run - m_new);   // first tile: exp(-huge) = 0
            s_lane *= alpha;
            #pragma unroll
            for (int ks = 0; ks < 4; ++ks)
                #pragma unroll
                for (int j = 0; j < 8; ++j) opart[ks][j] *= alpha;
            m_run = m_new;
        }
        const float p = __expf(lg - m_run);              // dup/masked rows -> 0
        s_lane += p;
        #pragma unroll
        for (int ks = 0; ks < 4; ++ks) {
            opart[ks][0] = fmaf(p, a0[ks].x, opart[ks][0]);
            opart[ks][1] = fmaf(p, a0[ks].y, opart[ks][1]);
            opart[ks][2] = fmaf(p, a0[ks].z, opart[ks][2]);
            opart[ks][3] = fmaf(p, a0[ks].w, opart[ks][3]);
            opart[ks][4] = fmaf(p, a1[ks].x, opart[ks][4]);
            opart[ks][5] = fmaf(p, a1[ks].y, opart[ks][5]);
            opart[ks][6] = fmaf(p, a1[ks].z, opart[ks][6]);
            opart[ks][7] = fmaf(p, a1[ks].w, opart[ks][7]);
        }
    }

    // per-wave totals
    float S_w = s_lane;
    #pragma unroll
    for (int m = 1; m < 16; m <<= 1) S_w += __shfl_xor(S_w, m);
    if (lane == 0) { mw[wv] = m_run; sw[wv] = S_w; }
    __syncthreads();
    const float M = fmaxf(fmaxf(mw[0], mw[1]), fmaxf(mw[2], mw[3]));
    const float Stot = sw[0] * __expf(mw[0] - M) + sw[1] * __expf(mw[1] - M)
                     + sw[2] * __expf(mw[2] - M) + sw[3] * __expf(mw[3] - M);
    const float beta = __expf(m_run - M) * __builtin_amdgcn_rcpf(Stot);

    #pragma unroll
    for (int ks = 0; ks < 4; ++ks)
        #pragma unroll
        for (int j = 0; j < 8; ++j) {
            float v = opart[ks][j] * beta;
            #pragma unroll
            for (int m = 1; m < 16; m <<= 1) v += __shfl_xor(v, m);  // sum over rows
            if (l15 == 0) osum[wv][ks * 32 + quad * 8 + j] = v;
        }
    __syncthreads();
    if (tid < 128)
        out[bs * Ddim + tid] = (osum[0][tid] + osum[1][tid]) + (osum[2][tid] + osum[3][tid]);
}

extern "C" void kernel_launch(void* const* d_in, const int* in_sizes, int n_in,
                              void* d_out, int out_size, void* d_ws, size_t ws_size,
                              hipStream_t stream) {
    const float* X    = (const float*)d_in[0];
    const float* z    = (const float*)d_in[1];
    const int*   mask = (const int*)d_in[2];
    const float* W1   = (const float*)d_in[3];
    const float* W2w  = (const float*)d_in[4];
    const float* W2b  = (const float*)d_in[5];
    const float* Vw   = (const float*)d_in[6];
    const float* Vb   = (const float*)d_in[7];
    float* out = (float*)d_out;

    unsigned short* W1bf = (unsigned short*)d_ws;            // 8192 bf16 = 16 KB
    float* w2h = (float*)((char*)d_ws + 16384);              // 3200*64 fp32 = 800 KB

    prep<<<804, 256, 0, stream>>>(z, W2w, W2b, W1, W1bf, w2h);
    attn_main<<<NBS, 256, 0, stream>>>(X, mask, Vw, Vb, W1bf, w2h, out);
}